// Round 11
// baseline (54.136 us; speedup 1.0000x reference)
//
#include <hip/hip_runtime.h>

// s[n,k] = x[n]·coords[k] + ||coords[k]||^2 ; out[n,k] = (second_min_j s[n,j]) > s[n,k]
// 512 blocks x 512 threads (2 blocks/CU via (512,2); VGPR cap 128). Block: 32 rows x 128 cols.
// Wave g = K-split (32 dims). x-tile (32x256=32KB) staged ONCE (slot-XOR swizzle), then a
// barrier-free main loop: B read direct from global (L2-hot coords, dot-product form),
// A from LDS, 2048 FMA/thread. Epilogue: plane exchange part[4][32][132] (aliases xs).

__global__ __launch_bounds__(512, 2)
void kmad_main(const float* __restrict__ x, const float* __restrict__ coords,
               int* __restrict__ out) {
    __shared__ float lds[17024];          // 66.6 KB
    float* const xs    = lds;             // [32][256], slot q stored at q^(row>>3)
    float* const norms = lds + 16896;     // [128]
    float* const part  = lds;             // epilogue alias [4][32][132] = 16896 floats

    const int t  = threadIdx.x;
    const int g  = t >> 6;                // wave = K-split 0..7 (dims g*32..+32)
    const int l  = t & 63;
    const int rg = l >> 4;                // rows rg*8..+8
    const int cg = l & 15;                // cols cg*8..+8
    const int r0 = rg * 8;
    const int c0 = cg * 8;
    const int row0 = blockIdx.x * 32;

    // ---- norms[c] = ||coords[c]||^2 ----
    {
        const int c = t >> 2, h = t & 3;
        const float4* cp = (const float4*)(coords + (size_t)c * 256 + h * 64);
        float na = 0.f;
        #pragma unroll
        for (int k = 0; k < 16; ++k) {
            const float4 v = cp[k];
            na = fmaf(v.x, v.x, na); na = fmaf(v.y, v.y, na);
            na = fmaf(v.z, v.z, na); na = fmaf(v.w, v.w, na);
        }
        na += __shfl_xor(na, 1); na += __shfl_xor(na, 2);
        if (h == 0) norms[c] = na;
    }

    // ---- stage full x block: 32 rows x 256 dims, coalesced, swizzled ----
    {
        const int srow = t >> 4, sk = t & 15;
        const float* xr = x + (size_t)(row0 + srow) * 256;
        float* xw = xs + srow * 256;
        const int sw = srow >> 3;
        #pragma unroll
        for (int k = 0; k < 4; ++k) {
            const int q = sk + 16 * k;
            *(float4*)(xw + (q ^ sw) * 4) = *(const float4*)(xr + q * 4);
        }
    }
    __syncthreads();   // the ONLY barrier before the epilogue

    // ---- main loop: 8 d4-steps, no barriers ----
    float acc[8][8] = {};
    const float* bp0 = coords + (size_t)(c0 + 0) * 256 + g * 32;   // cols c0..c0+3
    const float* bp1 = coords + (size_t)(c0 + 4) * 256 + g * 32;   // cols c0+4..c0+7
    const float* ap  = xs + (size_t)r0 * 256 + g * 32;             // + i*256 + (d4^rg)*4

    #pragma unroll
    for (int d4 = 0; d4 < 8; ++d4) {
        float4 b[8];
        #pragma unroll
        for (int cc = 0; cc < 4; ++cc) {
            b[cc]     = *(const float4*)(bp0 + cc * 256 + d4 * 4);
            b[cc + 4] = *(const float4*)(bp1 + cc * 256 + d4 * 4);
        }
        const int aoff = (d4 ^ rg) * 4;
        #pragma unroll
        for (int i = 0; i < 8; ++i) {
            const float4 a = *(const float4*)(ap + i * 256 + aoff);
            #pragma unroll
            for (int cc = 0; cc < 8; ++cc) {
                acc[i][cc] = fmaf(a.x, b[cc].x, acc[i][cc]);
                acc[i][cc] = fmaf(a.y, b[cc].y, acc[i][cc]);
                acc[i][cc] = fmaf(a.z, b[cc].z, acc[i][cc]);
                acc[i][cc] = fmaf(a.w, b[cc].w, acc[i][cc]);
            }
        }
    }
    __syncthreads();   // xs dead -> part alias safe

    // ---- reduce 8 split-partials via 4 planes, 2 rounds ----
    if (g < 4) {
        float* pl = part + g * 4224 + (size_t)r0 * 132 + c0;
        #pragma unroll
        for (int i = 0; i < 8; ++i) {
            *(float4*)(pl + i * 132)     = make_float4(acc[i][0], acc[i][1], acc[i][2], acc[i][3]);
            *(float4*)(pl + i * 132 + 4) = make_float4(acc[i][4], acc[i][5], acc[i][6], acc[i][7]);
        }
    }
    __syncthreads();
    if (g >= 4) {
        float* pl = part + (g - 4) * 4224 + (size_t)r0 * 132 + c0;
        #pragma unroll
        for (int i = 0; i < 8; ++i) {
            float4 v0 = *(const float4*)(pl + i * 132);
            float4 v1 = *(const float4*)(pl + i * 132 + 4);
            v0.x += acc[i][0]; v0.y += acc[i][1]; v0.z += acc[i][2]; v0.w += acc[i][3];
            v1.x += acc[i][4]; v1.y += acc[i][5]; v1.z += acc[i][6]; v1.w += acc[i][7];
            *(float4*)(pl + i * 132)     = v0;
            *(float4*)(pl + i * 132 + 4) = v1;
        }
    }
    __syncthreads();

    // ---- final: sum 4 planes, +norms, second-min over 128, compare, store ----
    {
        const int frow = t >> 4, seg = t & 15;       // 32 rows x 16 col-segments of 8
        const float* pr = part + (size_t)frow * 132 + seg * 8;
        float s[8];
        #pragma unroll
        for (int u = 0; u < 2; ++u) {
            const float4 a = *(const float4*)(pr + u * 4);
            const float4 b = *(const float4*)(pr + 4224  + u * 4);
            const float4 c = *(const float4*)(pr + 8448  + u * 4);
            const float4 d = *(const float4*)(pr + 12672 + u * 4);
            const float4 n = *(const float4*)(norms + seg * 8 + u * 4);
            s[u * 4 + 0] = (a.x + b.x) + (c.x + d.x) + n.x;
            s[u * 4 + 1] = (a.y + b.y) + (c.y + d.y) + n.y;
            s[u * 4 + 2] = (a.z + b.z) + (c.z + d.z) + n.z;
            s[u * 4 + 3] = (a.w + b.w) + (c.w + d.w) + n.w;
        }
        float m1 = fminf(s[0], s[1]);
        float m2 = fmaxf(s[0], s[1]);
#define UPD(v) { const float hi = fmaxf(m1, (v)); m1 = fminf(m1, (v)); m2 = fminf(m2, hi); }
        UPD(s[2]) UPD(s[3]) UPD(s[4]) UPD(s[5]) UPD(s[6]) UPD(s[7])
#undef UPD
        #pragma unroll
        for (int m = 1; m <= 8; m <<= 1) {   // merge across the 16 seg lanes
            const float o1 = __shfl_xor(m1, m);
            const float o2 = __shfl_xor(m2, m);
            m2 = fminf(fmaxf(m1, o1), fminf(m2, o2));
            m1 = fminf(m1, o1);
        }
        int* op = out + (size_t)(row0 + frow) * 128 + seg * 8;
        int4 o0, o1v;
        o0.x  = m2 > s[0]; o0.y  = m2 > s[1]; o0.z  = m2 > s[2]; o0.w  = m2 > s[3];
        o1v.x = m2 > s[4]; o1v.y = m2 > s[5]; o1v.z = m2 > s[6]; o1v.w = m2 > s[7];
        *(int4*)op       = o0;
        *(int4*)(op + 4) = o1v;
    }
}

extern "C" void kernel_launch(void* const* d_in, const int* in_sizes, int n_in,
                              void* d_out, int out_size, void* d_ws, size_t ws_size,
                              hipStream_t stream) {
    const float* x      = (const float*)d_in[0];   // (16384, 256) fp32
    const float* coords = (const float*)d_in[1];   // (128, 256)   fp32
    int* out = (int*)d_out;                        // (16384, 128) bool -> int32 0/1
    kmad_main<<<512, 512, 0, stream>>>(x, coords, out);
}

// Round 12
// 28.407 us; speedup vs baseline: 1.9057x; 1.9057x over previous
//
#include <hip/hip_runtime.h>

// s[n,k] = x[n]·coords[k] + ||coords[k]||^2 ; out[n,k] = (second_min_j s[n,j]) > s[n,k]
// 512 blocks x 512 threads, __launch_bounds__(512,2) = 2 blocks/CU (VGPR cap 128, no spill),
// 16 waves/CU. Block: 32 rows x 128 cols. Wave = K-split g (8 splits); chunk = 32 dims
// (8 chunks); split g owns quad g of each chunk. Thread tile 8x8, dot-product form:
// both A and B read as float4 over dims.
//   xs[32][256] resident: quad q of row r stored at slot q^(r>>3)  -> A-reads broadcast,
//     4 distinct quads per instr, conflict-free.
//   cs[2][128][32] dbuf: quad ql of col c stored at ql^((c>>3)&7) -> B-reads spread over
//     8 quads, 2 cols each (free). Staging = straight coalesced copy (NO transpose).
//   T14: global loads issued at chunk top, LDS writes after FMA block, 1 barrier/chunk.
//   norms accumulated from the staging registers (no separate coords pre-pass).
// Epilogue: plane exchange part[4][32][132] (aliases xs+cs) + second-min (R10-verified).

__global__ __launch_bounds__(512, 2)
void kmad_main(const float* __restrict__ x, const float* __restrict__ coords,
               int* __restrict__ out) {
    __shared__ float lds[17024];         // 66.5 KB
    float* const xs    = lds;            // [32][256]
    float* const cs    = lds + 8192;     // [2][128][32]
    float* const norms = lds + 16896;    // [128]
    float* const part  = lds;            // epilogue alias [4][32][132] = 16896 floats

    const int t  = threadIdx.x;
    const int g  = t >> 6;               // wave = K-split 0..7
    const int l  = t & 63;
    const int rg = l >> 4;               // rows rg*8..+8
    const int cg = l & 15;               // cols cg*8..+8
    const int r0 = rg * 8;
    const int c0 = cg * 8;
    const int row0 = blockIdx.x * 32;

    // ---- xs stage once (coalesced read, row-keyed quad swizzle on write) ----
    {
        const int srow = t >> 4, m = t & 15;
        const float* xr = x + (size_t)(row0 + srow) * 256;
        float* xw = xs + srow * 256;
        const int key = srow >> 3;       // 0..3
        #pragma unroll
        for (int k = 0; k < 4; ++k) {
            const int q = m + 16 * k;
            *(float4*)(xw + (q ^ key) * 4) = *(const float4*)(xr + q * 4);
        }
    }

    // ---- cs staging roles: thread owns col scol, 8-dim slice sqp ----
    const int scol = t >> 2, sqp = t & 3;
    const float* crd = coords + (size_t)scol * 256 + sqp * 8;   // + ch*32
    const int ckey = (scol >> 3) & 7;
    float* const csw0 = cs + scol * 32 + (((sqp * 2)     ^ ckey) * 4);
    float* const csw1 = cs + scol * 32 + (((sqp * 2 + 1) ^ ckey) * 4);

    float na = 0.f;                      // partial ||coords[scol]||^2 (dims sqp-slice)
    {   // chunk 0 stage
        const float4 p0 = *(const float4*)(crd);
        const float4 p1 = *(const float4*)(crd + 4);
        na = fmaf(p0.x,p0.x,na); na = fmaf(p0.y,p0.y,na);
        na = fmaf(p0.z,p0.z,na); na = fmaf(p0.w,p0.w,na);
        na = fmaf(p1.x,p1.x,na); na = fmaf(p1.y,p1.y,na);
        na = fmaf(p1.z,p1.z,na); na = fmaf(p1.w,p1.w,na);
        *(float4*)csw0 = p0;
        *(float4*)csw1 = p1;
    }
    __syncthreads();

    float acc[8][8] = {};
    const float* ap0 = xs + (size_t)r0 * 256;                    // + i*256 + aslot
    const float* bp0 = cs + (size_t)c0 * 32 + (g ^ (cg & 7)) * 4; // + buf + hc*32

    #pragma unroll
    for (int ch = 0; ch < 8; ++ch) {
        const int buf = (ch & 1) * 4096;
        // T14: issue next chunk's global loads FIRST (hide under FMAs)
        float4 p0, p1;
        if (ch < 7) {
            p0 = *(const float4*)(crd + (ch + 1) * 32);
            p1 = *(const float4*)(crd + (ch + 1) * 32 + 4);
        }
        const int aslot = ((ch * 8 + g) ^ rg) * 4;
        const float* bp = bp0 + buf;
        #pragma unroll
        for (int half = 0; half < 2; ++half) {
            const float4 b0 = *(const float4*)(bp + (half * 4 + 0) * 32);
            const float4 b1 = *(const float4*)(bp + (half * 4 + 1) * 32);
            const float4 b2 = *(const float4*)(bp + (half * 4 + 2) * 32);
            const float4 b3 = *(const float4*)(bp + (half * 4 + 3) * 32);
            #pragma unroll
            for (int i = 0; i < 8; ++i) {
                const float4 a = *(const float4*)(ap0 + i * 256 + aslot);
#define FM(J, B) \
                acc[i][half*4+J] = fmaf(a.x, B.x, acc[i][half*4+J]); \
                acc[i][half*4+J] = fmaf(a.y, B.y, acc[i][half*4+J]); \
                acc[i][half*4+J] = fmaf(a.z, B.z, acc[i][half*4+J]); \
                acc[i][half*4+J] = fmaf(a.w, B.w, acc[i][half*4+J]);
                FM(0, b0) FM(1, b1) FM(2, b2) FM(3, b3)
#undef FM
            }
        }
        if (ch < 7) {   // write staged chunk into the other buffer (after compute)
            na = fmaf(p0.x,p0.x,na); na = fmaf(p0.y,p0.y,na);
            na = fmaf(p0.z,p0.z,na); na = fmaf(p0.w,p0.w,na);
            na = fmaf(p1.x,p1.x,na); na = fmaf(p1.y,p1.y,na);
            na = fmaf(p1.z,p1.z,na); na = fmaf(p1.w,p1.w,na);
            *(float4*)(csw0 + (4096 - buf)) = p0;
            *(float4*)(csw1 + (4096 - buf)) = p1;
        }
        __syncthreads();
    }

    // ---- norms: reduce the 4 sqp-slices of col scol, write (visible after next barrier) ----
    na += __shfl_xor(na, 1);
    na += __shfl_xor(na, 2);
    if (sqp == 0) norms[scol] = na;

    // ---- reduce 8 split-partials via 4 planes, 2 rounds (part aliases xs+cs) ----
    if (g < 4) {
        float* pl = part + g * 4224 + (size_t)r0 * 132 + c0;
        #pragma unroll
        for (int i = 0; i < 8; ++i) {
            *(float4*)(pl + i * 132)     = make_float4(acc[i][0], acc[i][1], acc[i][2], acc[i][3]);
            *(float4*)(pl + i * 132 + 4) = make_float4(acc[i][4], acc[i][5], acc[i][6], acc[i][7]);
        }
    }
    __syncthreads();
    if (g >= 4) {
        float* pl = part + (g - 4) * 4224 + (size_t)r0 * 132 + c0;
        #pragma unroll
        for (int i = 0; i < 8; ++i) {
            float4 v0 = *(const float4*)(pl + i * 132);
            float4 v1 = *(const float4*)(pl + i * 132 + 4);
            v0.x += acc[i][0]; v0.y += acc[i][1]; v0.z += acc[i][2]; v0.w += acc[i][3];
            v1.x += acc[i][4]; v1.y += acc[i][5]; v1.z += acc[i][6]; v1.w += acc[i][7];
            *(float4*)(pl + i * 132)     = v0;
            *(float4*)(pl + i * 132 + 4) = v1;
        }
    }
    __syncthreads();

    // ---- final: sum 4 planes, +norms, second-min over 128, compare, store ----
    {
        const int frow = t >> 4, seg = t & 15;       // 32 rows x 16 col-segments of 8
        const float* pr = part + (size_t)frow * 132 + seg * 8;
        float s[8];
        #pragma unroll
        for (int u = 0; u < 2; ++u) {
            const float4 a = *(const float4*)(pr + u * 4);
            const float4 b = *(const float4*)(pr + 4224  + u * 4);
            const float4 c = *(const float4*)(pr + 8448  + u * 4);
            const float4 d = *(const float4*)(pr + 12672 + u * 4);
            const float4 n = *(const float4*)(norms + seg * 8 + u * 4);
            s[u * 4 + 0] = (a.x + b.x) + (c.x + d.x) + n.x;
            s[u * 4 + 1] = (a.y + b.y) + (c.y + d.y) + n.y;
            s[u * 4 + 2] = (a.z + b.z) + (c.z + d.z) + n.z;
            s[u * 4 + 3] = (a.w + b.w) + (c.w + d.w) + n.w;
        }
        float m1 = fminf(s[0], s[1]);
        float m2 = fmaxf(s[0], s[1]);
#define UPD(v) { const float hi = fmaxf(m1, (v)); m1 = fminf(m1, (v)); m2 = fminf(m2, hi); }
        UPD(s[2]) UPD(s[3]) UPD(s[4]) UPD(s[5]) UPD(s[6]) UPD(s[7])
#undef UPD
        #pragma unroll
        for (int m = 1; m <= 8; m <<= 1) {   // merge across the 16 seg lanes
            const float o1 = __shfl_xor(m1, m);
            const float o2 = __shfl_xor(m2, m);
            m2 = fminf(fmaxf(m1, o1), fminf(m2, o2));
            m1 = fminf(m1, o1);
        }
        int* op = out + (size_t)(row0 + frow) * 128 + seg * 8;
        int4 o0, o1v;
        o0.x  = m2 > s[0]; o0.y  = m2 > s[1]; o0.z  = m2 > s[2]; o0.w  = m2 > s[3];
        o1v.x = m2 > s[4]; o1v.y = m2 > s[5]; o1v.z = m2 > s[6]; o1v.w = m2 > s[7];
        *(int4*)op       = o0;
        *(int4*)(op + 4) = o1v;
    }
}

extern "C" void kernel_launch(void* const* d_in, const int* in_sizes, int n_in,
                              void* d_out, int out_size, void* d_ws, size_t ws_size,
                              hipStream_t stream) {
    const float* x      = (const float*)d_in[0];   // (16384, 256) fp32
    const float* coords = (const float*)d_in[1];   // (128, 256)   fp32
    int* out = (int*)d_out;                        // (16384, 128) bool -> int32 0/1
    kmad_main<<<512, 512, 0, stream>>>(x, coords, out);
}

// Round 13
// 27.131 us; speedup vs baseline: 1.9954x; 1.0470x over previous
//
#include <hip/hip_runtime.h>

// s[n,k] = x[n]·coords[k] + ||coords[k]||^2 ; out[n,k] = (second_min_j s[n,j]) > s[n,k]
// 512 blocks x 512 threads, __launch_bounds__(512,1): 1 block/CU resident (VGPR cap 256),
// 8 waves/CU. Block: 32 rows x 128 cols. Wave g = K-split (owns quad g of each 32-dim
// chunk -> 32 dims total). Thread tile 8x8, dot-product form.
// FULL residency: xs[32][256] (32KB) + cs[128][256] (128KB) = 160.0 KB -> main loop has
// ZERO barriers (the R10/R12 barrier-stall was ~60% of time). Layouts identical to R12's
// verified patterns: xs quad q of row r at slot q^(r>>3); cs chunk-local quad ql of col c
// at slot ql^((c>>3)&7). Epilogue plane-exchange + norms alias the cs region.

__global__ __launch_bounds__(512, 1)
void kmad_main(const float* __restrict__ x, const float* __restrict__ coords,
               int* __restrict__ out) {
    __shared__ float lds[40960];          // 160.0 KB (CDNA4 max)
    float* const xs    = lds;             // [32][256]
    float* const cs    = lds + 8192;      // [128][256]
    float* const part  = lds + 8192;      // epilogue alias [4][32][132] = 16896 floats
    float* const norms = lds + 25088;     // epilogue alias [128]

    const int t  = threadIdx.x;
    const int g  = t >> 6;                // wave = K-split 0..7
    const int l  = t & 63;
    const int rg = l >> 4;                // rows rg*8..+8
    const int cg = l & 15;                // cols cg*8..+8
    const int r0 = rg * 8;
    const int c0 = cg * 8;
    const int row0 = blockIdx.x * 32;

    // ---- xs stage once (coalesced read, row-keyed quad swizzle) ----
    {
        const int srow = t >> 4, m = t & 15;
        const float* xr = x + (size_t)(row0 + srow) * 256;
        float* xw = xs + srow * 256;
        const int key = srow >> 3;
        #pragma unroll
        for (int k = 0; k < 4; ++k) {
            const int q = m + 16 * k;
            *(float4*)(xw + (q ^ key) * 4) = *(const float4*)(xr + q * 4);
        }
    }

    // ---- cs stage: all 8 chunks (R12's staging pattern), norms partial in regs ----
    const int scol = t >> 2, sqp = t & 3;
    const float* crd = coords + (size_t)scol * 256 + sqp * 8;
    const int ckey = (scol >> 3) & 7;
    float* const csw0 = cs + (size_t)scol * 256 + (((sqp * 2)     ^ ckey) * 4);
    float* const csw1 = cs + (size_t)scol * 256 + (((sqp * 2 + 1) ^ ckey) * 4);
    float na = 0.f;
    #pragma unroll
    for (int ch = 0; ch < 8; ++ch) {
        const float4 p0 = *(const float4*)(crd + ch * 32);
        const float4 p1 = *(const float4*)(crd + ch * 32 + 4);
        na = fmaf(p0.x,p0.x,na); na = fmaf(p0.y,p0.y,na);
        na = fmaf(p0.z,p0.z,na); na = fmaf(p0.w,p0.w,na);
        na = fmaf(p1.x,p1.x,na); na = fmaf(p1.y,p1.y,na);
        na = fmaf(p1.z,p1.z,na); na = fmaf(p1.w,p1.w,na);
        *(float4*)(csw0 + ch * 32) = p0;
        *(float4*)(csw1 + ch * 32) = p1;
    }
    __syncthreads();   // the ONLY barrier before the epilogue

    // ---- main loop: 8 chunks, barrier-free ----
    float acc[8][8] = {};
    const float* ap0 = xs + (size_t)r0 * 256;                      // + i*256 + aslot
    const float* bp0 = cs + (size_t)c0 * 256 + (g ^ (cg & 7)) * 4; // + cc*256 + ch*32

    #pragma unroll
    for (int ch = 0; ch < 8; ++ch) {
        const int aslot = ((ch * 8 + g) ^ rg) * 4;
        const float* bp = bp0 + ch * 32;
        float4 b[8];
        #pragma unroll
        for (int cc = 0; cc < 8; ++cc)
            b[cc] = *(const float4*)(bp + cc * 256);
        #pragma unroll
        for (int i = 0; i < 8; ++i) {
            const float4 a = *(const float4*)(ap0 + i * 256 + aslot);
            #pragma unroll
            for (int cc = 0; cc < 8; ++cc) {
                acc[i][cc] = fmaf(a.x, b[cc].x, acc[i][cc]);
                acc[i][cc] = fmaf(a.y, b[cc].y, acc[i][cc]);
                acc[i][cc] = fmaf(a.z, b[cc].z, acc[i][cc]);
                acc[i][cc] = fmaf(a.w, b[cc].w, acc[i][cc]);
            }
        }
    }
    __syncthreads();   // xs/cs dead -> part/norms aliases safe

    // ---- norms finalize (stager lanes) + plane A writes ----
    na += __shfl_xor(na, 1);
    na += __shfl_xor(na, 2);
    if (sqp == 0) norms[scol] = na;

    if (g < 4) {
        float* pl = part + g * 4224 + (size_t)r0 * 132 + c0;
        #pragma unroll
        for (int i = 0; i < 8; ++i) {
            *(float4*)(pl + i * 132)     = make_float4(acc[i][0], acc[i][1], acc[i][2], acc[i][3]);
            *(float4*)(pl + i * 132 + 4) = make_float4(acc[i][4], acc[i][5], acc[i][6], acc[i][7]);
        }
    }
    __syncthreads();
    if (g >= 4) {
        float* pl = part + (g - 4) * 4224 + (size_t)r0 * 132 + c0;
        #pragma unroll
        for (int i = 0; i < 8; ++i) {
            float4 v0 = *(const float4*)(pl + i * 132);
            float4 v1 = *(const float4*)(pl + i * 132 + 4);
            v0.x += acc[i][0]; v0.y += acc[i][1]; v0.z += acc[i][2]; v0.w += acc[i][3];
            v1.x += acc[i][4]; v1.y += acc[i][5]; v1.z += acc[i][6]; v1.w += acc[i][7];
            *(float4*)(pl + i * 132)     = v0;
            *(float4*)(pl + i * 132 + 4) = v1;
        }
    }
    __syncthreads();

    // ---- final: sum 4 planes, +norms, second-min over 128, compare, store ----
    {
        const int frow = t >> 4, seg = t & 15;       // 32 rows x 16 col-segments of 8
        const float* pr = part + (size_t)frow * 132 + seg * 8;
        float s[8];
        #pragma unroll
        for (int u = 0; u < 2; ++u) {
            const float4 a = *(const float4*)(pr + u * 4);
            const float4 b = *(const float4*)(pr + 4224  + u * 4);
            const float4 c = *(const float4*)(pr + 8448  + u * 4);
            const float4 d = *(const float4*)(pr + 12672 + u * 4);
            const float4 n = *(const float4*)(norms + seg * 8 + u * 4);
            s[u * 4 + 0] = (a.x + b.x) + (c.x + d.x) + n.x;
            s[u * 4 + 1] = (a.y + b.y) + (c.y + d.y) + n.y;
            s[u * 4 + 2] = (a.z + b.z) + (c.z + d.z) + n.z;
            s[u * 4 + 3] = (a.w + b.w) + (c.w + d.w) + n.w;
        }
        float m1 = fminf(s[0], s[1]);
        float m2 = fmaxf(s[0], s[1]);
#define UPD(v) { const float hi = fmaxf(m1, (v)); m1 = fminf(m1, (v)); m2 = fminf(m2, hi); }
        UPD(s[2]) UPD(s[3]) UPD(s[4]) UPD(s[5]) UPD(s[6]) UPD(s[7])
#undef UPD
        #pragma unroll
        for (int m = 1; m <= 8; m <<= 1) {   // merge across the 16 seg lanes
            const float o1 = __shfl_xor(m1, m);
            const float o2 = __shfl_xor(m2, m);
            m2 = fminf(fmaxf(m1, o1), fminf(m2, o2));
            m1 = fminf(m1, o1);
        }
        int* op = out + (size_t)(row0 + frow) * 128 + seg * 8;
        int4 o0, o1v;
        o0.x  = m2 > s[0]; o0.y  = m2 > s[1]; o0.z  = m2 > s[2]; o0.w  = m2 > s[3];
        o1v.x = m2 > s[4]; o1v.y = m2 > s[5]; o1v.z = m2 > s[6]; o1v.w = m2 > s[7];
        *(int4*)op       = o0;
        *(int4*)(op + 4) = o1v;
    }
}

extern "C" void kernel_launch(void* const* d_in, const int* in_sizes, int n_in,
                              void* d_out, int out_size, void* d_ws, size_t ws_size,
                              hipStream_t stream) {
    const float* x      = (const float*)d_in[0];   // (16384, 256) fp32
    const float* coords = (const float*)d_in[1];   // (128, 256)   fp32
    int* out = (int*)d_out;                        // (16384, 128) bool -> int32 0/1
    kmad_main<<<512, 512, 0, stream>>>(x, coords, out);
}